// Round 1
// baseline (243.766 us; speedup 1.0000x reference)
//
#include <hip/hip_runtime.h>
#include <hip/hip_bf16.h>

#define NN 500000
#define NSEG 1024
#define NT ((NN + 127) / 128)   // 3907 tiles of 128 elements

typedef __bf16 bf16x8 __attribute__((ext_vector_type(8)));
typedef float  f32x4  __attribute__((ext_vector_type(4)));

// ---------------------------------------------------------------------------
// prep: segment-start table, bf16 transposed/padded weights, folded V = Wk.Wq/8
// ---------------------------------------------------------------------------
__global__ void prep_kernel(const int* __restrict__ seg,
                            const float* __restrict__ W0,
                            const float* __restrict__ W1,
                            const float* __restrict__ Wl,
                            const float* __restrict__ Wk,
                            const float* __restrict__ Wq,
                            int* __restrict__ starts,
                            __bf16* __restrict__ W0t,
                            __bf16* __restrict__ W1t,
                            __bf16* __restrict__ Wlt,
                            float* __restrict__ Vx,
                            float* __restrict__ Vagg) {
  int tid = blockIdx.x * blockDim.x + threadIdx.x;
  int stride = gridDim.x * blockDim.x;
  // starts[t] = first n with seg[n] >= t, for t in [0, NSEG]
  for (int n = tid; n < NN; n += stride) {
    int s = seg[n];
    int sp = (n == 0) ? -1 : seg[n - 1];
    for (int t = sp + 1; t <= s; ++t) starts[t] = n;
    if (n == NN - 1) { for (int t = s + 1; t <= NSEG; ++t) starts[t] = NN; }
  }
  // transposed bf16 weights, k-padded: W0t [128][40] (K 16->32 pad + 8), W1t/Wlt [128][136]
  for (int i = tid; i < 5120 + 2 * 17408; i += stride) {
    if (i < 5120) {
      int j = i / 40, k = i % 40;
      W0t[i] = (__bf16)((k < 16) ? W0[k * 128 + j] : 0.0f);
    } else if (i < 5120 + 17408) {
      int i2 = i - 5120; int j = i2 / 136, k = i2 % 136;
      W1t[i2] = (__bf16)((k < 128) ? W1[k * 128 + j] : 0.0f);
    } else {
      int i2 = i - 5120 - 17408; int j = i2 / 136, k = i2 % 136;
      Wlt[i2] = (__bf16)((k < 128) ? Wl[k * 128 + j] : 0.0f);
    }
  }
  // V[c][h] = sum_d Wk[c, h*64+d] * Wq[h, d], pre-scaled by 1/sqrt(64)
  for (int i = tid; i < 144 * 4; i += stride) {
    int c = i >> 2, h = i & 3;
    float a = 0.f;
    for (int d = 0; d < 64; ++d) a = fmaf(Wk[c * 256 + h * 64 + d], Wq[h * 64 + d], a);
    a *= 0.125f;
    if (c < 16) Vx[c * 4 + h] = a; else Vagg[(c - 16) * 4 + h] = a;
  }
}

// ---------------------------------------------------------------------------
// Fused 3-layer bf16 MFMA MLP + segment-sum of enc
// ---------------------------------------------------------------------------
template<int KSTEPS, bool TRANS>
__device__ __forceinline__ void layer_mfma(const __bf16* A, int sA,
                                           const __bf16* B, int sB,
                                           const float* bias,
                                           __bf16* O, int sO,
                                           int rb, int cb, int lrow, int q) {
  f32x4 acc[4][4] = {};
#pragma unroll
  for (int s = 0; s < KSTEPS; ++s) {
    bf16x8 fa[4], fb[4];
#pragma unroll
    for (int i = 0; i < 4; ++i)
      fa[i] = *(const bf16x8*)(A + (rb + 16 * i + lrow) * sA + s * 32 + q * 8);
#pragma unroll
    for (int j = 0; j < 4; ++j)
      fb[j] = *(const bf16x8*)(B + (cb + 16 * j + lrow) * sB + s * 32 + q * 8);
#pragma unroll
    for (int i = 0; i < 4; ++i)
#pragma unroll
      for (int j = 0; j < 4; ++j)
        acc[i][j] = __builtin_amdgcn_mfma_f32_16x16x32_bf16(fa[i], fb[j], acc[i][j], 0, 0, 0);
  }
#pragma unroll
  for (int j = 0; j < 4; ++j) {
    int col = cb + 16 * j + lrow;        // output feature
    float bv = bias[col];
#pragma unroll
    for (int i = 0; i < 4; ++i) {
#pragma unroll
      for (int r = 0; r < 4; ++r) {
        int row = rb + 16 * i + 4 * q + r;   // element
        float v = acc[i][j][r] + bv;
        v = v > 0.f ? v : 0.f;
        if (TRANS) O[col * sO + row] = (__bf16)v;
        else       O[row * sO + col] = (__bf16)v;
      }
    }
  }
  __syncthreads();
}

__launch_bounds__(256, 1)
__global__ void mlp_kernel(const float* __restrict__ x, const int* __restrict__ seg,
                           const float* __restrict__ b0, const float* __restrict__ b1,
                           const float* __restrict__ bl,
                           const __bf16* __restrict__ W0t, const __bf16* __restrict__ W1t,
                           const __bf16* __restrict__ Wlt,
                           float* __restrict__ seg_sum, float* __restrict__ counts) {
  __shared__ __align__(16) __bf16 sW0[128 * 40];
  __shared__ __align__(16) __bf16 sW1[128 * 136];
  __shared__ __align__(16) __bf16 sWl[128 * 136];
  __shared__ __align__(16) __bf16 sX [128 * 40];
  __shared__ __align__(16) __bf16 sH0[128 * 136];   // h0, later enc_t [feat][elem]
  __shared__ __align__(16) __bf16 sH1[128 * 136];
  __shared__ float sB0[128], sB1[128], sBl[128];
  __shared__ __align__(16) int sSeg[128];

  int t = threadIdx.x;
  for (int i = t; i < 640;  i += 256) ((uint4*)sW0)[i] = ((const uint4*)W0t)[i];
  for (int i = t; i < 2176; i += 256) ((uint4*)sW1)[i] = ((const uint4*)W1t)[i];
  for (int i = t; i < 2176; i += 256) ((uint4*)sWl)[i] = ((const uint4*)Wlt)[i];
  if (t < 128) { sB0[t] = b0[t]; sB1[t] = b1[t]; sBl[t] = bl[t]; }
  for (int i = t; i < 2560; i += 256) ((unsigned int*)sX)[i] = 0u;  // zero incl. K-pad
  __syncthreads();

  int wave = t >> 6, lane = t & 63;
  int rb = (wave >> 1) * 64, cb = (wave & 1) * 64;
  int lrow = lane & 15, q = lane >> 4;

  for (int tile = blockIdx.x; tile < NT; tile += gridDim.x) {
    int base = tile * 128;
    int m = min(128, NN - base);
    {
      int e = t >> 1, ko = (t & 1) * 8;
      if (e < m) {
        const float* xp = x + (size_t)(base + e) * 16 + ko;
        float4 v0 = *(const float4*)xp;
        float4 v1 = *(const float4*)(xp + 4);
        __bf16* d = sX + e * 40 + ko;
        d[0]=(__bf16)v0.x; d[1]=(__bf16)v0.y; d[2]=(__bf16)v0.z; d[3]=(__bf16)v0.w;
        d[4]=(__bf16)v1.x; d[5]=(__bf16)v1.y; d[6]=(__bf16)v1.z; d[7]=(__bf16)v1.w;
      }
      if (t < 128) sSeg[t] = (t < m) ? seg[base + t] : -1;
    }
    __syncthreads();

    layer_mfma<1, false>(sX , 40 , sW0, 40 , sB0, sH0, 136, rb, cb, lrow, q);
    layer_mfma<4, false>(sH0, 136, sW1, 136, sB1, sH1, 136, rb, cb, lrow, q);
    layer_mfma<4, true >(sH1, 136, sWl, 136, sBl, sH0, 136, rb, cb, lrow, q);

    // run-length segment accumulation from enc_t = sH0 [feat j][elem e]
    {
      int j = t & 127, half = t >> 7;
      int e0 = half * 64;
      int e1 = min(m, e0 + 64);
      float a = 0.f, c = 0.f; int cur = -1;
      for (int e = e0; e < e1; e += 8) {
        bf16x8 v8 = *(const bf16x8*)(sH0 + j * 136 + e);
        int4 sa = *(const int4*)(sSeg + e);
        int4 sb = *(const int4*)(sSeg + e + 4);
        int ss[8] = { sa.x, sa.y, sa.z, sa.w, sb.x, sb.y, sb.z, sb.w };
#pragma unroll
        for (int k = 0; k < 8; ++k) {
          int sgn = ss[k];
          if (sgn != cur) {           // wave-uniform branch (same e-sequence all lanes)
            if (cur >= 0) {
              atomicAdd(&seg_sum[cur * 128 + j], a);
              if (j == 0) atomicAdd(&counts[cur], c);
            }
            a = 0.f; c = 0.f; cur = sgn;
          }
          a += (float)v8[k]; c += 1.f;
        }
      }
      if (cur >= 0) {
        atomicAdd(&seg_sum[cur * 128 + j], a);
        if (j == 0) atomicAdd(&counts[cur], c);
      }
    }
    __syncthreads();
  }
}

// ---------------------------------------------------------------------------
// rho on segment means + fold with Vagg -> segterm[s][h]
// ---------------------------------------------------------------------------
__launch_bounds__(128)
__global__ void rho_kernel(const float* __restrict__ seg_sum, const float* __restrict__ counts,
                           const float* __restrict__ Wr, const float* __restrict__ br,
                           const float* __restrict__ Vagg, float* __restrict__ segterm) {
  int s = blockIdx.x, j = threadIdx.x;
  __shared__ float sm[128];
  __shared__ float wred[2][4];
  float inv = 1.f / fmaxf(counts[s], 1.f);
  sm[j] = seg_sum[s * 128 + j] * inv;
  __syncthreads();
  float a = br[j];
#pragma unroll 8
  for (int k = 0; k < 128; ++k) a = fmaf(sm[k], Wr[k * 128 + j], a);
  a = fmaxf(a, 0.f);
  float4 vh = *(const float4*)(Vagg + j * 4);
  float p0 = a * vh.x, p1 = a * vh.y, p2 = a * vh.z, p3 = a * vh.w;
  for (int o = 1; o < 64; o <<= 1) {
    p0 += __shfl_xor(p0, o); p1 += __shfl_xor(p1, o);
    p2 += __shfl_xor(p2, o); p3 += __shfl_xor(p3, o);
  }
  int w = j >> 6;
  if ((j & 63) == 0) { wred[w][0]=p0; wred[w][1]=p1; wred[w][2]=p2; wred[w][3]=p3; }
  __syncthreads();
  if (j == 0) {
    segterm[s*4+0] = wred[0][0] + wred[1][0];
    segterm[s*4+1] = wred[0][1] + wred[1][1];
    segterm[s*4+2] = wred[0][2] + wred[1][2];
    segterm[s*4+3] = wred[0][3] + wred[1][3];
  }
}

// ---------------------------------------------------------------------------
// per-segment softmax attention (block per segment; d_out doubles as scratch)
// ---------------------------------------------------------------------------
__launch_bounds__(256)
__global__ void attn_kernel(const float* __restrict__ x, const int* __restrict__ starts,
                            const float* __restrict__ Vx, const float* __restrict__ segterm,
                            float* __restrict__ out) {
  int s = blockIdx.x, t = threadIdx.x;
  __shared__ float sVx[64];
  __shared__ float sST[4];
  __shared__ int rng[2];
  __shared__ float r1[4][4], r2[4][4];
  __shared__ float mbc[4], dbc[4];
  if (t < 64) sVx[t] = Vx[t];
  if (t < 4) sST[t] = segterm[s * 4 + t];
  if (t == 0) { rng[0] = starts[s]; rng[1] = starts[s + 1]; }
  __syncthreads();
  int lo = rng[0], hi = rng[1];
  if (lo >= hi) return;   // empty segment (uniform)
  float m0=-1e30f, m1=-1e30f, m2=-1e30f, m3=-1e30f;
  for (int n = lo + t; n < hi; n += 256) {
    const float* xp = x + (size_t)n * 16;
    float4 a0 = *(const float4*)xp, a1 = *(const float4*)(xp+4),
           a2 = *(const float4*)(xp+8), a3 = *(const float4*)(xp+12);
    float xv[16] = {a0.x,a0.y,a0.z,a0.w, a1.x,a1.y,a1.z,a1.w,
                    a2.x,a2.y,a2.z,a2.w, a3.x,a3.y,a3.z,a3.w};
    float p0=sST[0], p1=sST[1], p2=sST[2], p3=sST[3];
#pragma unroll
    for (int k = 0; k < 16; ++k) {
      p0 = fmaf(xv[k], sVx[k*4+0], p0);
      p1 = fmaf(xv[k], sVx[k*4+1], p1);
      p2 = fmaf(xv[k], sVx[k*4+2], p2);
      p3 = fmaf(xv[k], sVx[k*4+3], p3);
    }
    float4 pv = {p0,p1,p2,p3};
    *(float4*)(out + (size_t)n * 4) = pv;
    m0=fmaxf(m0,p0); m1=fmaxf(m1,p1); m2=fmaxf(m2,p2); m3=fmaxf(m3,p3);
  }
  for (int o = 1; o < 64; o <<= 1) {
    m0=fmaxf(m0,__shfl_xor(m0,o)); m1=fmaxf(m1,__shfl_xor(m1,o));
    m2=fmaxf(m2,__shfl_xor(m2,o)); m3=fmaxf(m3,__shfl_xor(m3,o));
  }
  int w = t >> 6;
  if ((t & 63) == 0) { r1[w][0]=m0; r1[w][1]=m1; r1[w][2]=m2; r1[w][3]=m3; }
  __syncthreads();
  if (t < 4) mbc[t] = fmaxf(fmaxf(r1[0][t], r1[1][t]), fmaxf(r1[2][t], r1[3][t]));
  __syncthreads();
  float M0=mbc[0], M1=mbc[1], M2=mbc[2], M3=mbc[3];
  float s0=0.f, s1=0.f, s2=0.f, s3=0.f;
  for (int n = lo + t; n < hi; n += 256) {
    float4 p = *(const float4*)(out + (size_t)n * 4);
    float4 e = { __expf(p.x - M0), __expf(p.y - M1), __expf(p.z - M2), __expf(p.w - M3) };
    *(float4*)(out + (size_t)n * 4) = e;
    s0+=e.x; s1+=e.y; s2+=e.z; s3+=e.w;
  }
  for (int o = 1; o < 64; o <<= 1) {
    s0+=__shfl_xor(s0,o); s1+=__shfl_xor(s1,o);
    s2+=__shfl_xor(s2,o); s3+=__shfl_xor(s3,o);
  }
  if ((t & 63) == 0) { r2[w][0]=s0; r2[w][1]=s1; r2[w][2]=s2; r2[w][3]=s3; }
  __syncthreads();
  if (t < 4) dbc[t] = r2[0][t]+r2[1][t]+r2[2][t]+r2[3][t];
  __syncthreads();
  float i0=1.f/dbc[0], i1=1.f/dbc[1], i2=1.f/dbc[2], i3=1.f/dbc[3];
  for (int n = lo + t; n < hi; n += 256) {
    float4 e = *(const float4*)(out + (size_t)n * 4);
    e.x*=i0; e.y*=i1; e.z*=i2; e.w*=i3;
    *(float4*)(out + (size_t)n * 4) = e;
  }
}

// ---------------------------------------------------------------------------
extern "C" void kernel_launch(void* const* d_in, const int* in_sizes, int n_in,
                              void* d_out, int out_size, void* d_ws, size_t ws_size,
                              hipStream_t stream) {
  const float* x   = (const float*)d_in[0];
  const int*   seg = (const int*)  d_in[1];
  // d_in[2] = lengths (unused by reference math)
  const float* W0  = (const float*)d_in[3];
  const float* b0  = (const float*)d_in[4];
  const float* W1  = (const float*)d_in[5];
  const float* b1  = (const float*)d_in[6];
  const float* Wl  = (const float*)d_in[7];
  const float* bl  = (const float*)d_in[8];
  const float* Wr  = (const float*)d_in[9];
  const float* br  = (const float*)d_in[10];
  const float* Wk  = (const float*)d_in[11];
  const float* Wq  = (const float*)d_in[12];
  float* out = (float*)d_out;

  char* ws = (char*)d_ws;
  float*  seg_sum = (float*)(ws);            // 1024*128 f32 = 524288 B
  float*  counts  = (float*)(ws + 524288);   // 1024 f32     =   4096 B
  float*  segterm = (float*)(ws + 528384);   // 1024*4 f32   =  16384 B
  float*  Vx      = (float*)(ws + 544768);   // 16*4 f32     =    256 B
  float*  Vagg    = (float*)(ws + 545024);   // 128*4 f32    =   2048 B
  int*    starts  = (int*)  (ws + 547072);   // 1025 i32     (pad to 4352 B)
  __bf16* W0t     = (__bf16*)(ws + 551424);  // 128*40  bf16 =  10240 B
  __bf16* W1t     = (__bf16*)(ws + 561664);  // 128*136 bf16 =  34816 B
  __bf16* Wlt     = (__bf16*)(ws + 596480);  // 128*136 bf16 =  34816 B  (end 631296)

  hipMemsetAsync(ws, 0, 528384, stream);  // seg_sum + counts

  hipLaunchKernelGGL(prep_kernel, dim3(512), dim3(256), 0, stream,
                     seg, W0, W1, Wl, Wk, Wq, starts, W0t, W1t, Wlt, Vx, Vagg);
  hipLaunchKernelGGL(mlp_kernel, dim3(256), dim3(256), 0, stream,
                     x, seg, b0, b1, bl, W0t, W1t, Wlt, seg_sum, counts);
  hipLaunchKernelGGL(rho_kernel, dim3(NSEG), dim3(128), 0, stream,
                     seg_sum, counts, Wr, br, Vagg, segterm);
  hipLaunchKernelGGL(attn_kernel, dim3(NSEG), dim3(256), 0, stream,
                     x, starts, Vx, segterm, out);
}

// Round 2
// 103.227 us; speedup vs baseline: 2.3615x; 2.3615x over previous
//
#include <hip/hip_runtime.h>

#define NN 500000
#define NSEG 1024
#define MAXE 2048   // per-segment in-LDS capacity (binomial max ~600; fallback beyond)

// ---------------------------------------------------------------------------
// prep: starts[t] = first n with seg[n] >= t (seg sorted), and folded
//       Vx[c][h] = sum_d Wk[c, h*64+d] * Wq[h,d] / sqrt(64), c<16 (x part only;
//       the agg part is constant per segment and cancels in the softmax)
// ---------------------------------------------------------------------------
__global__ void prep_kernel(const int* __restrict__ seg,
                            const float* __restrict__ Wk,
                            const float* __restrict__ Wq,
                            int* __restrict__ starts,
                            float* __restrict__ Vx) {
  int tid = blockIdx.x * blockDim.x + threadIdx.x;
  int stride = gridDim.x * blockDim.x;
  for (int n = tid; n < NN; n += stride) {
    int s = seg[n];
    int sp = (n == 0) ? -1 : seg[n - 1];
    for (int t = sp + 1; t <= s; ++t) starts[t] = n;
    if (n == NN - 1) { for (int t = s + 1; t <= NSEG; ++t) starts[t] = NN; }
  }
  if (tid < 64) {
    int c = tid >> 2, h = tid & 3;
    float a = 0.f;
    for (int d = 0; d < 64; ++d) a = fmaf(Wk[c * 256 + h * 64 + d], Wq[h * 64 + d], a);
    Vx[tid] = a * 0.125f;
  }
}

// ---------------------------------------------------------------------------
// attn: one block per segment. pre -> LDS -> max -> exp/sum -> scale -> out.
// x read once (32 MB), out written once (8 MB). Global 3-pass fallback for
// segments longer than MAXE (never expected for this distribution).
// ---------------------------------------------------------------------------
__launch_bounds__(256, 4)
__global__ void attn_kernel(const float* __restrict__ x,
                            const int* __restrict__ starts,
                            const float* __restrict__ Vx,
                            float* __restrict__ out) {
  __shared__ float4 sPre[MAXE];      // 32 KB
  __shared__ float4 sVx4[16];
  __shared__ float red[4][4];
  __shared__ float bc[4];
  __shared__ int rng[2];

  int s = blockIdx.x, t = threadIdx.x;
  if (t < 16) sVx4[t] = ((const float4*)Vx)[t];
  if (t < 2)  rng[t] = starts[s + t];
  __syncthreads();
  int lo = rng[0], hi = rng[1], len = hi - lo;
  if (len <= 0) return;   // uniform across block

  int w = t >> 6;

  if (len <= MAXE) {
    // ---- phase 1: pre -> LDS, track per-thread max
    float m0 = -1e30f, m1 = -1e30f, m2 = -1e30f, m3 = -1e30f;
    for (int i = t; i < len; i += 256) {
      const float4* xp = (const float4*)(x + (size_t)(lo + i) * 16);
      float4 a0 = xp[0], a1 = xp[1], a2 = xp[2], a3 = xp[3];
      float xv[16] = {a0.x,a0.y,a0.z,a0.w, a1.x,a1.y,a1.z,a1.w,
                      a2.x,a2.y,a2.z,a2.w, a3.x,a3.y,a3.z,a3.w};
      float p0 = 0.f, p1 = 0.f, p2 = 0.f, p3 = 0.f;
#pragma unroll
      for (int k = 0; k < 16; ++k) {
        float4 vh = sVx4[k];
        p0 = fmaf(xv[k], vh.x, p0);
        p1 = fmaf(xv[k], vh.y, p1);
        p2 = fmaf(xv[k], vh.z, p2);
        p3 = fmaf(xv[k], vh.w, p3);
      }
      sPre[i] = (float4){p0, p1, p2, p3};
      m0 = fmaxf(m0, p0); m1 = fmaxf(m1, p1);
      m2 = fmaxf(m2, p2); m3 = fmaxf(m3, p3);
    }
    for (int o = 1; o < 64; o <<= 1) {
      m0 = fmaxf(m0, __shfl_xor(m0, o)); m1 = fmaxf(m1, __shfl_xor(m1, o));
      m2 = fmaxf(m2, __shfl_xor(m2, o)); m3 = fmaxf(m3, __shfl_xor(m3, o));
    }
    if ((t & 63) == 0) { red[w][0]=m0; red[w][1]=m1; red[w][2]=m2; red[w][3]=m3; }
    __syncthreads();
    if (t < 4) bc[t] = fmaxf(fmaxf(red[0][t], red[1][t]), fmaxf(red[2][t], red[3][t]));
    __syncthreads();
    float M0 = bc[0], M1 = bc[1], M2 = bc[2], M3 = bc[3];

    // ---- phase 2: exp in LDS, track per-thread sum
    float s0 = 0.f, s1 = 0.f, s2 = 0.f, s3 = 0.f;
    for (int i = t; i < len; i += 256) {
      float4 p = sPre[i];
      float4 e = { __expf(p.x - M0), __expf(p.y - M1),
                   __expf(p.z - M2), __expf(p.w - M3) };
      sPre[i] = e;
      s0 += e.x; s1 += e.y; s2 += e.z; s3 += e.w;
    }
    for (int o = 1; o < 64; o <<= 1) {
      s0 += __shfl_xor(s0, o); s1 += __shfl_xor(s1, o);
      s2 += __shfl_xor(s2, o); s3 += __shfl_xor(s3, o);
    }
    __syncthreads();   // everyone done reading bc(M) and red
    if ((t & 63) == 0) { red[w][0]=s0; red[w][1]=s1; red[w][2]=s2; red[w][3]=s3; }
    __syncthreads();
    if (t < 4) bc[t] = 1.f / (red[0][t] + red[1][t] + red[2][t] + red[3][t]);
    __syncthreads();
    float i0 = bc[0], i1 = bc[1], i2 = bc[2], i3 = bc[3];

    // ---- phase 3: scale + store
    for (int i = t; i < len; i += 256) {
      float4 e = sPre[i];
      e.x *= i0; e.y *= i1; e.z *= i2; e.w *= i3;
      *(float4*)(out + (size_t)(lo + i) * 4) = e;
    }
  } else {
    // ---- fallback: 3 passes via global memory (out doubles as scratch)
    float m0 = -1e30f, m1 = -1e30f, m2 = -1e30f, m3 = -1e30f;
    for (int i = t; i < len; i += 256) {
      const float4* xp = (const float4*)(x + (size_t)(lo + i) * 16);
      float4 a0 = xp[0], a1 = xp[1], a2 = xp[2], a3 = xp[3];
      float xv[16] = {a0.x,a0.y,a0.z,a0.w, a1.x,a1.y,a1.z,a1.w,
                      a2.x,a2.y,a2.z,a2.w, a3.x,a3.y,a3.z,a3.w};
      float p0 = 0.f, p1 = 0.f, p2 = 0.f, p3 = 0.f;
#pragma unroll
      for (int k = 0; k < 16; ++k) {
        float4 vh = sVx4[k];
        p0 = fmaf(xv[k], vh.x, p0);
        p1 = fmaf(xv[k], vh.y, p1);
        p2 = fmaf(xv[k], vh.z, p2);
        p3 = fmaf(xv[k], vh.w, p3);
      }
      *(float4*)(out + (size_t)(lo + i) * 4) = (float4){p0, p1, p2, p3};
      m0 = fmaxf(m0, p0); m1 = fmaxf(m1, p1);
      m2 = fmaxf(m2, p2); m3 = fmaxf(m3, p3);
    }
    for (int o = 1; o < 64; o <<= 1) {
      m0 = fmaxf(m0, __shfl_xor(m0, o)); m1 = fmaxf(m1, __shfl_xor(m1, o));
      m2 = fmaxf(m2, __shfl_xor(m2, o)); m3 = fmaxf(m3, __shfl_xor(m3, o));
    }
    if ((t & 63) == 0) { red[w][0]=m0; red[w][1]=m1; red[w][2]=m2; red[w][3]=m3; }
    __syncthreads();
    if (t < 4) bc[t] = fmaxf(fmaxf(red[0][t], red[1][t]), fmaxf(red[2][t], red[3][t]));
    __syncthreads();
    float M0 = bc[0], M1 = bc[1], M2 = bc[2], M3 = bc[3];

    float s0 = 0.f, s1 = 0.f, s2 = 0.f, s3 = 0.f;
    for (int i = t; i < len; i += 256) {
      float4 p = *(const float4*)(out + (size_t)(lo + i) * 4);
      float4 e = { __expf(p.x - M0), __expf(p.y - M1),
                   __expf(p.z - M2), __expf(p.w - M3) };
      *(float4*)(out + (size_t)(lo + i) * 4) = e;
      s0 += e.x; s1 += e.y; s2 += e.z; s3 += e.w;
    }
    for (int o = 1; o < 64; o <<= 1) {
      s0 += __shfl_xor(s0, o); s1 += __shfl_xor(s1, o);
      s2 += __shfl_xor(s2, o); s3 += __shfl_xor(s3, o);
    }
    __syncthreads();
    if ((t & 63) == 0) { red[w][0]=s0; red[w][1]=s1; red[w][2]=s2; red[w][3]=s3; }
    __syncthreads();
    if (t < 4) bc[t] = 1.f / (red[0][t] + red[1][t] + red[2][t] + red[3][t]);
    __syncthreads();
    float i0 = bc[0], i1 = bc[1], i2 = bc[2], i3 = bc[3];

    for (int i = t; i < len; i += 256) {
      float4 e = *(const float4*)(out + (size_t)(lo + i) * 4);
      e.x *= i0; e.y *= i1; e.z *= i2; e.w *= i3;
      *(float4*)(out + (size_t)(lo + i) * 4) = e;
    }
  }
}

// ---------------------------------------------------------------------------
extern "C" void kernel_launch(void* const* d_in, const int* in_sizes, int n_in,
                              void* d_out, int out_size, void* d_ws, size_t ws_size,
                              hipStream_t stream) {
  const float* x   = (const float*)d_in[0];
  const int*   seg = (const int*)  d_in[1];
  // d_in[2..10] (lengths, W0,b0,W1,b1,Wlat,blat,Wrho,brho) cancel in the
  // per-segment softmax (shift-invariance) — mathematically unused.
  const float* Wk  = (const float*)d_in[11];
  const float* Wq  = (const float*)d_in[12];
  float* out = (float*)d_out;

  int*   starts = (int*)d_ws;                    // 1025 ints
  float* Vx     = (float*)((char*)d_ws + 4352);  // 64 floats, 16B-aligned

  hipLaunchKernelGGL(prep_kernel, dim3(512), dim3(256), 0, stream,
                     seg, Wk, Wq, starts, Vx);
  hipLaunchKernelGGL(attn_kernel, dim3(NSEG), dim3(256), 0, stream,
                     x, starts, Vx, out);
}